// Round 5
// baseline (255.016 us; speedup 1.0000x reference)
//
#include <hip/hip_runtime.h>
#include <hip/hip_bf16.h>

// Problem dims (fixed): B=8, L=128, H=768, R=24
#define BD   8
#define LD   128
#define HD   768
#define RD   24
#define H2D  384
#define NF   1536   // fused N (two heads side by side)

typedef __attribute__((ext_vector_type(8))) short bf16x8;
typedef __attribute__((ext_vector_type(4))) float f32x4;

__device__ __forceinline__ short f2bf(float f) {
    __hip_bfloat16 h = __float2bfloat16(f);
    return *reinterpret_cast<short*>(&h);
}

// ---------------------------------------------------------------------------
// Kernel 1: everything small. grid(B), 1024 threads.
//  - pool[b]  (LDS)
//  - rel_hidden -> stage1 -> out[0:192]
//  - biasrel[b,n] = re@W_top[:,n] + bias   (ws, consumed by biggemm)
//  - init out_subj/out_obj with b_st/b_ot  (biggemm atomically accumulates)
__global__ __launch_bounds__(1024) void small_kernel(
        const float* __restrict__ embed, const float* __restrict__ mask,
        const float* __restrict__ W_hr, const float* __restrict__ b_hr,
        const float* __restrict__ W_rj, const float* __restrict__ b_rj,
        const float* __restrict__ rel_emb, const int* __restrict__ trel,
        const float* __restrict__ W_sh, const float* __restrict__ b_sh,
        const float* __restrict__ W_oh, const float* __restrict__ b_oh,
        const float* __restrict__ b_st, const float* __restrict__ b_ot,
        float* __restrict__ out_stage1, float* __restrict__ out_subj,
        float* __restrict__ out_obj, float* __restrict__ biasrel) {
    __shared__ float mrow[LD];
    __shared__ float prow[HD];
    __shared__ float re[HD];
    __shared__ float rpart[2][H2D];
    __shared__ float rh[H2D];
    __shared__ float spart[8][RD];
    __shared__ float msum;
    const int b = blockIdx.x, tid = threadIdx.x;

    // init subj/obj outputs with bias (atomics will accumulate on top)
    if (tid < 3 * LD) {
        const int l = tid / 3, t = tid - 3 * l;
        out_subj[(b * LD + l) * 3 + t] = b_st[t];
        out_obj [(b * LD + l) * 3 + t] = b_ot[t];
    }
    if (tid < LD) mrow[tid] = mask[b * LD + tid];
    if (tid >= 128 && tid < 128 + HD) {
        const int rel = trel[b];
        re[tid - 128] = rel_emb[(size_t)rel * HD + (tid - 128)];
    }
    __syncthreads();
    if (tid == 0) {
        float s = 0.f;
        for (int l = 0; l < LD; ++l) s += mrow[l];
        msum = s;
    }
    __syncthreads();

    // pool (768 threads, one h each)
    if (tid < HD) {
        float acc = 0.f;
        const float* base = embed + (size_t)b * LD * HD + tid;
#pragma unroll 8
        for (int l = 0; l < LD; ++l) acc += base[(size_t)l * HD] * mrow[l];
        prow[tid] = acc / msum;
    }

    // biasrel: all 1024 threads, cols stride 1024 (uses re, independent of prow)
    for (int col = tid; col < NF; col += 1024) {
        const float* Wp; float bb; int c;
        if (col < HD) { Wp = W_sh; bb = b_sh[col];      c = col; }
        else          { Wp = W_oh; bb = b_oh[col - HD]; c = col - HD; }
        float acc = 0.f;
#pragma unroll 8
        for (int k = 0; k < HD; ++k) acc += re[k] * Wp[(size_t)k * HD + c];
        biasrel[b * NF + col] = acc + bb;
    }
    __syncthreads();

    // rel_hidden: 768 threads (n x 2-way split-k)
    if (tid < 2 * H2D) {
        int n = tid, kc = 0;
        if (n >= H2D) { n -= H2D; kc = 1; }
        float acc = 0.f;
#pragma unroll 8
        for (int i = 0; i < H2D; ++i) {
            const int k = kc * H2D + i;
            acc += prow[k] * W_hr[(size_t)k * H2D + n];
        }
        rpart[kc][n] = acc;
    }
    __syncthreads();
    if (tid < H2D) rh[tid] = fmaxf(rpart[0][tid] + rpart[1][tid] + b_hr[tid], 0.f);
    __syncthreads();

    // stage1: 192 threads (24 n x 8-way split-k)
    if (tid < 8 * RD) {
        const int n = tid % RD, kc = tid / RD;
        float acc = 0.f;
#pragma unroll 8
        for (int i = 0; i < 48; ++i) {
            const int k = kc * 48 + i;
            acc += rh[k] * W_rj[k * RD + n];
        }
        spart[kc][n] = acc;
    }
    __syncthreads();
    if (tid < RD) {
        float s = b_rj[tid];
#pragma unroll
        for (int q = 0; q < 8; ++q) s += spart[q][tid];
        out_stage1[b * RD + tid] = s;
    }
}

// ---------------------------------------------------------------------------
// Kernel 2: both GEMMs in one dispatch, sharing the A (embed) LDS tile.
// grid (24, 16), 256 threads (4 waves, each 32x32 macro-tile).
//  GEMM0: AC[m, bn0..] = embed @ [W_corr0 | W_corr1]        (stored to ws)
//  GEMM1: v = relu(embed @ [W_shbot | W_ohbot] + biasrel)   (not stored;
//         reduced against W_st/W_ot into subj/obj via atomics)
__global__ __launch_bounds__(256) void biggemm(
        const float* __restrict__ embed,
        const float* __restrict__ W_corr,
        const float* __restrict__ W_shbot, const float* __restrict__ W_ohbot,
        const float* __restrict__ biasrel,
        const float* __restrict__ W_st, const float* __restrict__ W_ot,
        float* __restrict__ AC, float* __restrict__ out_subj,
        float* __restrict__ out_obj) {
    __shared__ __align__(16) short As [64][40];  // embed tile, bf16, pad 8
    __shared__ __align__(16) short Bs0[64][40];  // W_corr tile
    __shared__ __align__(16) short Bs1[64][40];  // W_*bot tile
    __shared__ float partial[64][3];

    const int tid = threadIdx.x;
    const int bn0 = blockIdx.x * 64;
    const int bm0 = blockIdx.y * 64;

    const float* Wc = (bn0 < HD) ? W_corr  : W_corr + (size_t)HD * HD;
    const float* Wh = (bn0 < HD) ? W_shbot : W_ohbot;
    const int col0 = (bn0 < HD) ? bn0 : bn0 - HD;

    if (tid < 192) partial[tid / 3][tid % 3] = 0.f;

    // staging indices
    const int am = tid >> 2;          // 0..63 (m row)
    const int ak = (tid & 3) * 4;     // 0,4,8,12
    const int bn = tid & 63;          // n row in Bs
    const int bk = (tid >> 6) * 8;    // 0,8,16,24

    // compute indices
    const int lane = tid & 63;
    const int wv = tid >> 6;
    const int wm = (wv >> 1) * 32;
    const int wn = (wv & 1) * 32;
    const int fr = lane & 15;
    const int kq = (lane >> 4) * 8;
    const int mq = (lane >> 4) * 4;

    f32x4 c00 = {0.f,0.f,0.f,0.f}, c01 = c00, c10 = c00, c11 = c00;   // GEMM0
    f32x4 h00 = c00, h01 = c00, h10 = c00, h11 = c00;                 // GEMM1

    for (int kt = 0; kt < 24; ++kt) {
        const int k0 = kt << 5;
        const float* arow = embed + (size_t)(bm0 + am) * HD + k0;
        float4 va0 = *(const float4*)(arow + ak);
        float4 va1 = *(const float4*)(arow + ak + 16);
        float vb0[8], vb1[8];
#pragma unroll
        for (int j = 0; j < 8; ++j) {
            const size_t widx = (size_t)(k0 + bk + j) * HD + col0 + bn;
            vb0[j] = Wc[widx];
            vb1[j] = Wh[widx];
        }

        __syncthreads();  // previous tile fully consumed
        {
            short4 s0 = { f2bf(va0.x), f2bf(va0.y), f2bf(va0.z), f2bf(va0.w) };
            short4 s1 = { f2bf(va1.x), f2bf(va1.y), f2bf(va1.z), f2bf(va1.w) };
            *(short4*)&As[am][ak]      = s0;
            *(short4*)&As[am][ak + 16] = s1;
            bf16x8 p0, p1;
#pragma unroll
            for (int j = 0; j < 8; ++j) { p0[j] = f2bf(vb0[j]); p1[j] = f2bf(vb1[j]); }
            *(bf16x8*)&Bs0[bn][bk] = p0;
            *(bf16x8*)&Bs1[bn][bk] = p1;
        }
        __syncthreads();

        bf16x8 a0 = *(bf16x8*)&As[wm + fr][kq];
        bf16x8 a1 = *(bf16x8*)&As[wm + 16 + fr][kq];
        bf16x8 b0 = *(bf16x8*)&Bs0[wn + fr][kq];
        bf16x8 b1 = *(bf16x8*)&Bs0[wn + 16 + fr][kq];
        bf16x8 d0 = *(bf16x8*)&Bs1[wn + fr][kq];
        bf16x8 d1 = *(bf16x8*)&Bs1[wn + 16 + fr][kq];
        c00 = __builtin_amdgcn_mfma_f32_16x16x32_bf16(a0, b0, c00, 0, 0, 0);
        c01 = __builtin_amdgcn_mfma_f32_16x16x32_bf16(a0, b1, c01, 0, 0, 0);
        c10 = __builtin_amdgcn_mfma_f32_16x16x32_bf16(a1, b0, c10, 0, 0, 0);
        c11 = __builtin_amdgcn_mfma_f32_16x16x32_bf16(a1, b1, c11, 0, 0, 0);
        h00 = __builtin_amdgcn_mfma_f32_16x16x32_bf16(a0, d0, h00, 0, 0, 0);
        h01 = __builtin_amdgcn_mfma_f32_16x16x32_bf16(a0, d1, h01, 0, 0, 0);
        h10 = __builtin_amdgcn_mfma_f32_16x16x32_bf16(a1, d0, h10, 0, 0, 0);
        h11 = __builtin_amdgcn_mfma_f32_16x16x32_bf16(a1, d1, h11, 0, 0, 0);
    }

    // ---- GEMM0 epilogue: store AC tile. C/D layout col=lane&15, row=quad*4+reg.
#pragma unroll
    for (int i = 0; i < 2; ++i) {
#pragma unroll
        for (int j = 0; j < 2; ++j) {
            f32x4 a = (i == 0) ? (j == 0 ? c00 : c01) : (j == 0 ? c10 : c11);
            const int ncol = bn0 + wn + j * 16 + fr;
#pragma unroll
            for (int r = 0; r < 4; ++r) {
                const int mrow = bm0 + wm + i * 16 + mq + r;
                AC[(size_t)mrow * NF + ncol] = a[r];
            }
        }
    }

    // ---- GEMM1 epilogue: relu(+biasrel), row-dot against W_st/W_ot, atomics.
    {
        const float* brl = biasrel + (size_t)(bm0 / LD) * NF;
        const float* Wt = (bn0 < HD) ? W_st : W_ot;
        float* op = (bn0 < HD) ? out_subj : out_obj;
        float pt[8][3] = {};
#pragma unroll
        for (int j = 0; j < 2; ++j) {
            const int ncol = bn0 + wn + j * 16 + fr;       // 0..1535
            const int ncl = (bn0 < HD) ? ncol : ncol - HD; // hidden idx 0..767
            const float wt0 = Wt[ncl * 3 + 0];
            const float wt1 = Wt[ncl * 3 + 1];
            const float wt2 = Wt[ncl * 3 + 2];
            const float bias = brl[ncol];
#pragma unroll
            for (int i = 0; i < 2; ++i) {
                f32x4 a = (i == 0) ? (j == 0 ? h00 : h01) : (j == 0 ? h10 : h11);
#pragma unroll
                for (int r = 0; r < 4; ++r) {
                    const float v = fmaxf(a[r] + bias, 0.f);
                    pt[i * 4 + r][0] += v * wt0;
                    pt[i * 4 + r][1] += v * wt1;
                    pt[i * 4 + r][2] += v * wt2;
                }
            }
        }
        // reduce over fr (16 lanes share the same 8 m-rows)
#pragma unroll
        for (int mask = 1; mask < 16; mask <<= 1) {
#pragma unroll
            for (int x = 0; x < 8; ++x)
#pragma unroll
                for (int t = 0; t < 3; ++t)
                    pt[x][t] += __shfl_xor(pt[x][t], mask, 64);
        }
        if (fr == 0) {
#pragma unroll
            for (int i = 0; i < 2; ++i)
#pragma unroll
                for (int r = 0; r < 4; ++r)
#pragma unroll
                    for (int t = 0; t < 3; ++t)
                        atomicAdd(&partial[wm + i * 16 + mq + r][t], pt[i * 4 + r][t]);
        }
        __syncthreads();
        if (tid < 192) {
            const int m = tid / 3, t = tid % 3;
            atomicAdd(&op[(size_t)(bm0 + m) * 3 + t], partial[m][t]);
        }
    }
}

// ---------------------------------------------------------------------------
// Kernel 3: pred_corres[b,i,j] = sum_h relu(A[b,j,h]+C[b,i,h]+b_corr[h])*W_gc[h]+b_gc
// AC row m=b*L+idx: A at cols [0,768), C at cols [768,1536)
__global__ void corres_kernel(const float* __restrict__ AC,
                              const float* __restrict__ b_corr, const float* __restrict__ W_gc,
                              const float* __restrict__ b_gc,
                              float* __restrict__ out) {
    const int b = blockIdx.y;
    const int i0 = blockIdx.x * 4;
    const int tid = threadIdx.x;
    const int lane = tid & 63;
    const int wave = tid >> 6;  // 0..3

    float wg[12], cb[4][12];
#pragma unroll
    for (int s = 0; s < 12; ++s) {
        const int h = lane + 64 * s;
        wg[s] = W_gc[h];
        const float bc = b_corr[h];
#pragma unroll
        for (int i = 0; i < 4; ++i)
            cb[i][s] = AC[((size_t)(b * LD + i0 + i)) * NF + HD + h] + bc;
    }
    const float bg = b_gc[0];

    for (int j = wave; j < LD; j += 4) {
        const float* arow = AC + ((size_t)(b * LD + j)) * NF;
        float a[12];
#pragma unroll
        for (int s = 0; s < 12; ++s) a[s] = arow[lane + 64 * s];
        float sum[4] = {0.f, 0.f, 0.f, 0.f};
#pragma unroll
        for (int s = 0; s < 12; ++s) {
#pragma unroll
            for (int i = 0; i < 4; ++i)
                sum[i] += fmaxf(a[s] + cb[i][s], 0.f) * wg[s];
        }
#pragma unroll
        for (int off = 32; off > 0; off >>= 1) {
#pragma unroll
            for (int i = 0; i < 4; ++i) sum[i] += __shfl_down(sum[i], off, 64);
        }
        if (lane == 0) {
#pragma unroll
            for (int i = 0; i < 4; ++i)
                out[((size_t)(b * LD + i0 + i)) * LD + j] = sum[i] + bg;
        }
    }
}

// ---------------------------------------------------------------------------
extern "C" void kernel_launch(void* const* d_in, const int* in_sizes, int n_in,
                              void* d_out, int out_size, void* d_ws, size_t ws_size,
                              hipStream_t stream) {
    const float* embed   = (const float*)d_in[0];
    const float* mask    = (const float*)d_in[1];
    const int*   trel    = (const int*)d_in[2];
    const float* W_hr    = (const float*)d_in[3];
    const float* b_hr    = (const float*)d_in[4];
    const float* W_rj    = (const float*)d_in[5];
    const float* b_rj    = (const float*)d_in[6];
    const float* rel_emb = (const float*)d_in[7];
    const float* W_corr  = (const float*)d_in[8];
    const float* b_corr  = (const float*)d_in[9];
    const float* W_gc    = (const float*)d_in[10];
    const float* b_gc    = (const float*)d_in[11];
    const float* W_sh    = (const float*)d_in[12];
    const float* b_sh    = (const float*)d_in[13];
    const float* W_st    = (const float*)d_in[14];
    const float* b_st    = (const float*)d_in[15];
    const float* W_oh    = (const float*)d_in[16];
    const float* b_oh    = (const float*)d_in[17];
    const float* W_ot    = (const float*)d_in[18];
    const float* b_ot    = (const float*)d_in[19];
    float* out = (float*)d_out;

    float* ws      = (float*)d_ws;
    float* AC      = ws;               // 1024*1536 floats
    float* biasrel = ws + 1572864;     // 8*1536 floats

    // Output layout: stage1[192] | subj[3072] | obj[3072] | pred_corres[131072]
    float* out_stage1 = out;
    float* out_subj   = out + 192;
    float* out_obj    = out + 3264;
    float* out_corr   = out + 6336;

    small_kernel<<<BD, 1024, 0, stream>>>(embed, mask, W_hr, b_hr, W_rj, b_rj,
                                          rel_emb, trel, W_sh, b_sh, W_oh, b_oh,
                                          b_st, b_ot, out_stage1, out_subj, out_obj,
                                          biasrel);

    dim3 ggrid(NF / 64, (BD * LD) / 64);  // (24, 16) = 384 blocks
    biggemm<<<ggrid, 256, 0, stream>>>(embed, W_corr,
                                       W_sh + (size_t)HD * HD, W_oh + (size_t)HD * HD,
                                       biasrel, W_st, W_ot,
                                       AC, out_subj, out_obj);

    corres_kernel<<<dim3(LD / 4, BD), 256, 0, stream>>>(AC, b_corr, W_gc, b_gc, out_corr);
}

// Round 6
// 174.846 us; speedup vs baseline: 1.4585x; 1.4585x over previous
//
#include <hip/hip_runtime.h>
#include <hip/hip_bf16.h>

// Problem dims (fixed): B=8, L=128, H=768, R=24
#define BD   8
#define LD   128
#define HD   768
#define RD   24
#define H2D  384
#define NF   1536   // fused N (two heads side by side)

typedef __attribute__((ext_vector_type(8))) short bf16x8;
typedef __attribute__((ext_vector_type(4))) float f32x4;

__device__ __forceinline__ short f2bf(float f) {
    __hip_bfloat16 h = __float2bfloat16(f);
    return *reinterpret_cast<short*>(&h);
}

// ---------------------------------------------------------------------------
// Launch 1: prep. grid (B, 24), 256 threads.
//  c in [0,12):  pool[b, c*64 .. c*64+64)   (4-way split over L)
//  c in [12,24): biasrel[b, (c-12)*128 ..]  = re@Wtop + bias  (2-way split-K)
//                c==12 also bias-inits out_subj/out_obj (biggemm atomic-adds)
__global__ __launch_bounds__(256) void prep_kernel(
        const float* __restrict__ embed, const float* __restrict__ mask,
        const float* __restrict__ rel_emb, const int* __restrict__ trel,
        const float* __restrict__ W_sh, const float* __restrict__ b_sh,
        const float* __restrict__ W_oh, const float* __restrict__ b_oh,
        const float* __restrict__ b_st, const float* __restrict__ b_ot,
        float* __restrict__ pool, float* __restrict__ biasrel,
        float* __restrict__ out_subj, float* __restrict__ out_obj) {
    const int b = blockIdx.x, c = blockIdx.y, tid = threadIdx.x;
    if (c < 12) {
        __shared__ float mrow[LD];
        __shared__ float msum;
        __shared__ float part[4][64];
        if (tid < LD) mrow[tid] = mask[b * LD + tid];
        __syncthreads();
        if (tid == 0) {
            float s = 0.f;
            for (int l = 0; l < LD; ++l) s += mrow[l];
            msum = s;
        }
        __syncthreads();
        const int lc = tid >> 6, hh = tid & 63;
        const int h = c * 64 + hh;
        float acc = 0.f;
        const float* base = embed + ((size_t)b * LD + lc * 32) * HD + h;
#pragma unroll 8
        for (int i = 0; i < 32; ++i) acc += base[(size_t)i * HD] * mrow[lc * 32 + i];
        part[lc][hh] = acc;
        __syncthreads();
        if (lc == 0)
            pool[b * HD + h] = (part[0][hh] + part[1][hh] + part[2][hh] + part[3][hh]) / msum;
    } else {
        const int cc = c - 12;
        __shared__ float re[HD];
        __shared__ float part2[2][128];
        const int rel = trel[b];
        for (int k = tid; k < HD; k += 256) re[k] = rel_emb[(size_t)rel * HD + k];
        if (cc == 0 && tid < 3 * LD) {
            const int l = tid / 3, t = tid - 3 * l;
            out_subj[(b * LD + l) * 3 + t] = b_st[t];
            out_obj [(b * LD + l) * 3 + t] = b_ot[t];
        }
        __syncthreads();
        const int kc = tid >> 7, nn = tid & 127;
        const int n = cc * 128 + nn;
        const float* Wp; float bb; int col;
        if (n < HD) { Wp = W_sh; bb = b_sh[n];      col = n; }
        else        { Wp = W_oh; bb = b_oh[n - HD]; col = n - HD; }
        float acc = 0.f;
#pragma unroll 8
        for (int i = 0; i < 384; ++i) {
            const int k = kc * 384 + i;
            acc += re[k] * Wp[(size_t)k * HD + col];
        }
        part2[kc][nn] = acc;
        __syncthreads();
        if (kc == 0) biasrel[b * NF + n] = part2[0][nn] + part2[1][nn] + bb;
    }
}

// ---------------------------------------------------------------------------
// Launch 2: biggemm. grid (27, 16), 256 threads.
//  x < 24: dual MFMA GEMM sharing the embed A-tile:
//    GEMM0: AC[m, bn0..] = embed @ [W_corr0 | W_corr1]       (store to ws)
//    GEMM1: relu(embed @ [W_shbot | W_ohbot] + biasrel) row-dotted against
//           W_st/W_ot -> atomicAdd into subj/obj
//  x >= 24: relh blocks (48): rh[b,n] = relu(pool@W_hr + b_hr)
__global__ __launch_bounds__(256) void biggemm(
        const float* __restrict__ embed,
        const float* __restrict__ W_corr,
        const float* __restrict__ W_shbot, const float* __restrict__ W_ohbot,
        const float* __restrict__ biasrel,
        const float* __restrict__ W_st, const float* __restrict__ W_ot,
        const float* __restrict__ pool,
        const float* __restrict__ W_hr, const float* __restrict__ b_hr,
        float* __restrict__ AC, float* __restrict__ out_subj,
        float* __restrict__ out_obj, float* __restrict__ rh) {
    const int tid = threadIdx.x;

    if (blockIdx.x >= 24) {
        // ---- relh block: b = y>>1, c = (x-24)*2 + (y&1)  -> 8 x 6 blocks
        const int b = blockIdx.y >> 1;
        const int c = (blockIdx.x - 24) * 2 + (blockIdx.y & 1);
        __shared__ float prow[HD];
        __shared__ float rpart[4][64];
        for (int k = tid; k < HD; k += 256) prow[k] = pool[b * HD + k];
        __syncthreads();
        const int kc = tid >> 6, nn = tid & 63;
        const int n = c * 64 + nn;
        float acc = 0.f;
#pragma unroll 8
        for (int i = 0; i < 192; ++i) {
            const int k = kc * 192 + i;
            acc += prow[k] * W_hr[(size_t)k * H2D + n];
        }
        rpart[kc][nn] = acc;
        __syncthreads();
        if (kc == 0)
            rh[b * H2D + n] = fmaxf(rpart[0][nn] + rpart[1][nn] + rpart[2][nn] + rpart[3][nn] + b_hr[n], 0.f);
        return;
    }

    __shared__ __align__(16) short As [64][40];  // embed tile, bf16, pad 8
    __shared__ __align__(16) short Bs0[64][40];  // W_corr tile
    __shared__ __align__(16) short Bs1[64][40];  // W_*bot tile
    __shared__ float partial[64][3];

    const int bn0 = blockIdx.x * 64;
    const int bm0 = blockIdx.y * 64;

    const float* Wc = (bn0 < HD) ? W_corr  : W_corr + (size_t)HD * HD;
    const float* Wh = (bn0 < HD) ? W_shbot : W_ohbot;
    const int col0 = (bn0 < HD) ? bn0 : bn0 - HD;

    if (tid < 192) partial[tid / 3][tid % 3] = 0.f;

    // staging indices
    const int am = tid >> 2;          // 0..63 (m row)
    const int ak = (tid & 3) * 4;     // 0,4,8,12
    const int bn = tid & 63;          // n row in Bs
    const int bk = (tid >> 6) * 8;    // 0,8,16,24

    // compute indices
    const int lane = tid & 63;
    const int wv = tid >> 6;
    const int wm = (wv >> 1) * 32;
    const int wn = (wv & 1) * 32;
    const int fr = lane & 15;
    const int kq = (lane >> 4) * 8;
    const int mq = (lane >> 4) * 4;

    f32x4 c00 = {0.f,0.f,0.f,0.f}, c01 = c00, c10 = c00, c11 = c00;   // GEMM0
    f32x4 h00 = c00, h01 = c00, h10 = c00, h11 = c00;                 // GEMM1

    for (int kt = 0; kt < 24; ++kt) {
        const int k0 = kt << 5;
        const float* arow = embed + (size_t)(bm0 + am) * HD + k0;
        float4 va0 = *(const float4*)(arow + ak);
        float4 va1 = *(const float4*)(arow + ak + 16);
        float vb0[8], vb1[8];
#pragma unroll
        for (int j = 0; j < 8; ++j) {
            const size_t widx = (size_t)(k0 + bk + j) * HD + col0 + bn;
            vb0[j] = Wc[widx];
            vb1[j] = Wh[widx];
        }

        __syncthreads();  // previous tile fully consumed
        {
            short4 s0 = { f2bf(va0.x), f2bf(va0.y), f2bf(va0.z), f2bf(va0.w) };
            short4 s1 = { f2bf(va1.x), f2bf(va1.y), f2bf(va1.z), f2bf(va1.w) };
            *(short4*)&As[am][ak]      = s0;
            *(short4*)&As[am][ak + 16] = s1;
            bf16x8 p0, p1;
#pragma unroll
            for (int j = 0; j < 8; ++j) { p0[j] = f2bf(vb0[j]); p1[j] = f2bf(vb1[j]); }
            *(bf16x8*)&Bs0[bn][bk] = p0;
            *(bf16x8*)&Bs1[bn][bk] = p1;
        }
        __syncthreads();

        bf16x8 a0 = *(bf16x8*)&As[wm + fr][kq];
        bf16x8 a1 = *(bf16x8*)&As[wm + 16 + fr][kq];
        bf16x8 b0 = *(bf16x8*)&Bs0[wn + fr][kq];
        bf16x8 b1 = *(bf16x8*)&Bs0[wn + 16 + fr][kq];
        bf16x8 d0 = *(bf16x8*)&Bs1[wn + fr][kq];
        bf16x8 d1 = *(bf16x8*)&Bs1[wn + 16 + fr][kq];
        c00 = __builtin_amdgcn_mfma_f32_16x16x32_bf16(a0, b0, c00, 0, 0, 0);
        c01 = __builtin_amdgcn_mfma_f32_16x16x32_bf16(a0, b1, c01, 0, 0, 0);
        c10 = __builtin_amdgcn_mfma_f32_16x16x32_bf16(a1, b0, c10, 0, 0, 0);
        c11 = __builtin_amdgcn_mfma_f32_16x16x32_bf16(a1, b1, c11, 0, 0, 0);
        h00 = __builtin_amdgcn_mfma_f32_16x16x32_bf16(a0, d0, h00, 0, 0, 0);
        h01 = __builtin_amdgcn_mfma_f32_16x16x32_bf16(a0, d1, h01, 0, 0, 0);
        h10 = __builtin_amdgcn_mfma_f32_16x16x32_bf16(a1, d0, h10, 0, 0, 0);
        h11 = __builtin_amdgcn_mfma_f32_16x16x32_bf16(a1, d1, h11, 0, 0, 0);
    }

    // ---- GEMM0 epilogue: store AC tile. C/D layout col=lane&15, row=quad*4+reg.
#pragma unroll
    for (int i = 0; i < 2; ++i) {
#pragma unroll
        for (int j = 0; j < 2; ++j) {
            f32x4 a = (i == 0) ? (j == 0 ? c00 : c01) : (j == 0 ? c10 : c11);
            const int ncol = bn0 + wn + j * 16 + fr;
#pragma unroll
            for (int r = 0; r < 4; ++r) {
                const int mrow = bm0 + wm + i * 16 + mq + r;
                AC[(size_t)mrow * NF + ncol] = a[r];
            }
        }
    }

    // ---- GEMM1 epilogue: relu(+biasrel), row-dot against W_st/W_ot, atomics.
    {
        const float* brl = biasrel + (size_t)(bm0 / LD) * NF;
        const float* Wt = (bn0 < HD) ? W_st : W_ot;
        float* op = (bn0 < HD) ? out_subj : out_obj;
        float pt[8][3] = {};
#pragma unroll
        for (int j = 0; j < 2; ++j) {
            const int ncol = bn0 + wn + j * 16 + fr;       // 0..1535
            const int ncl = (bn0 < HD) ? ncol : ncol - HD; // hidden idx 0..767
            const float wt0 = Wt[ncl * 3 + 0];
            const float wt1 = Wt[ncl * 3 + 1];
            const float wt2 = Wt[ncl * 3 + 2];
            const float bias = brl[ncol];
#pragma unroll
            for (int i = 0; i < 2; ++i) {
                f32x4 a = (i == 0) ? (j == 0 ? h00 : h01) : (j == 0 ? h10 : h11);
#pragma unroll
                for (int r = 0; r < 4; ++r) {
                    const float v = fmaxf(a[r] + bias, 0.f);
                    pt[i * 4 + r][0] += v * wt0;
                    pt[i * 4 + r][1] += v * wt1;
                    pt[i * 4 + r][2] += v * wt2;
                }
            }
        }
#pragma unroll
        for (int mask = 1; mask < 16; mask <<= 1) {
#pragma unroll
            for (int x = 0; x < 8; ++x)
#pragma unroll
                for (int t = 0; t < 3; ++t)
                    pt[x][t] += __shfl_xor(pt[x][t], mask, 64);
        }
        if (fr == 0) {
#pragma unroll
            for (int i = 0; i < 2; ++i)
#pragma unroll
                for (int r = 0; r < 4; ++r)
#pragma unroll
                    for (int t = 0; t < 3; ++t)
                        atomicAdd(&partial[wm + i * 16 + mq + r][t], pt[i * 4 + r][t]);
        }
        __syncthreads();
        if (tid < 192) {
            const int m = tid / 3, t = tid % 3;
            atomicAdd(&op[(size_t)(bm0 + m) * 3 + t], partial[m][t]);
        }
    }
}

// ---------------------------------------------------------------------------
// Launch 3: corres + stage1. grid (33, 8), 256 threads.
//  x < 32: pred_corres[b, i0..i0+4, :] ; x == 32: stage1 for batch y
__global__ void corres_kernel(const float* __restrict__ AC,
                              const float* __restrict__ b_corr, const float* __restrict__ W_gc,
                              const float* __restrict__ b_gc,
                              const float* __restrict__ rh,
                              const float* __restrict__ W_rj, const float* __restrict__ b_rj,
                              float* __restrict__ out, float* __restrict__ out_stage1) {
    const int b = blockIdx.y;
    const int tid = threadIdx.x;

    if (blockIdx.x == 32) {
        __shared__ float rl[H2D];
        __shared__ float spart[8][RD];
        for (int k = tid; k < H2D; k += 256) rl[k] = rh[b * H2D + k];
        __syncthreads();
        if (tid < 8 * RD) {
            const int n = tid % RD, kc = tid / RD;
            float acc = 0.f;
#pragma unroll 8
            for (int i = 0; i < 48; ++i) {
                const int k = kc * 48 + i;
                acc += rl[k] * W_rj[k * RD + n];
            }
            spart[kc][n] = acc;
        }
        __syncthreads();
        if (tid < RD) {
            float s = b_rj[tid];
#pragma unroll
            for (int q = 0; q < 8; ++q) s += spart[q][tid];
            out_stage1[b * RD + tid] = s;
        }
        return;
    }

    const int i0 = blockIdx.x * 4;
    const int lane = tid & 63;
    const int wave = tid >> 6;  // 0..3

    float wg[12], cb[4][12];
#pragma unroll
    for (int s = 0; s < 12; ++s) {
        const int h = lane + 64 * s;
        wg[s] = W_gc[h];
        const float bc = b_corr[h];
#pragma unroll
        for (int i = 0; i < 4; ++i)
            cb[i][s] = AC[((size_t)(b * LD + i0 + i)) * NF + HD + h] + bc;
    }
    const float bg = b_gc[0];

    for (int j = wave; j < LD; j += 4) {
        const float* arow = AC + ((size_t)(b * LD + j)) * NF;
        float a[12];
#pragma unroll
        for (int s = 0; s < 12; ++s) a[s] = arow[lane + 64 * s];
        float sum[4] = {0.f, 0.f, 0.f, 0.f};
#pragma unroll
        for (int s = 0; s < 12; ++s) {
#pragma unroll
            for (int i = 0; i < 4; ++i)
                sum[i] += fmaxf(a[s] + cb[i][s], 0.f) * wg[s];
        }
#pragma unroll
        for (int off = 32; off > 0; off >>= 1) {
#pragma unroll
            for (int i = 0; i < 4; ++i) sum[i] += __shfl_down(sum[i], off, 64);
        }
        if (lane == 0) {
#pragma unroll
            for (int i = 0; i < 4; ++i)
                out[((size_t)(b * LD + i0 + i)) * LD + j] = sum[i] + bg;
        }
    }
}

// ---------------------------------------------------------------------------
extern "C" void kernel_launch(void* const* d_in, const int* in_sizes, int n_in,
                              void* d_out, int out_size, void* d_ws, size_t ws_size,
                              hipStream_t stream) {
    const float* embed   = (const float*)d_in[0];
    const float* mask    = (const float*)d_in[1];
    const int*   trel    = (const int*)d_in[2];
    const float* W_hr    = (const float*)d_in[3];
    const float* b_hr    = (const float*)d_in[4];
    const float* W_rj    = (const float*)d_in[5];
    const float* b_rj    = (const float*)d_in[6];
    const float* rel_emb = (const float*)d_in[7];
    const float* W_corr  = (const float*)d_in[8];
    const float* b_corr  = (const float*)d_in[9];
    const float* W_gc    = (const float*)d_in[10];
    const float* b_gc    = (const float*)d_in[11];
    const float* W_sh    = (const float*)d_in[12];
    const float* b_sh    = (const float*)d_in[13];
    const float* W_st    = (const float*)d_in[14];
    const float* b_st    = (const float*)d_in[15];
    const float* W_oh    = (const float*)d_in[16];
    const float* b_oh    = (const float*)d_in[17];
    const float* W_ot    = (const float*)d_in[18];
    const float* b_ot    = (const float*)d_in[19];
    float* out = (float*)d_out;

    float* ws      = (float*)d_ws;
    float* AC      = ws;                           // 1024*1536 floats
    float* biasrel = ws + 1572864;                 // 8*1536
    float* rh      = ws + 1572864 + 12288;         // 8*384
    float* pool    = ws + 1572864 + 12288 + 3072;  // 8*768

    // Output layout: stage1[192] | subj[3072] | obj[3072] | pred_corres[131072]
    float* out_stage1 = out;
    float* out_subj   = out + 192;
    float* out_obj    = out + 3264;
    float* out_corr   = out + 6336;

    prep_kernel<<<dim3(BD, 24), 256, 0, stream>>>(embed, mask, rel_emb, trel,
                                                  W_sh, b_sh, W_oh, b_oh, b_st, b_ot,
                                                  pool, biasrel, out_subj, out_obj);

    biggemm<<<dim3(27, 16), 256, 0, stream>>>(embed, W_corr,
                                              W_sh + (size_t)HD * HD, W_oh + (size_t)HD * HD,
                                              biasrel, W_st, W_ot, pool, W_hr, b_hr,
                                              AC, out_subj, out_obj, rh);

    corres_kernel<<<dim3(33, BD), 256, 0, stream>>>(AC, b_corr, W_gc, b_gc,
                                                    rh, W_rj, b_rj, out_corr, out_stage1);
}

// Round 7
// 161.095 us; speedup vs baseline: 1.5830x; 1.0854x over previous
//
#include <hip/hip_runtime.h>
#include <hip/hip_bf16.h>

// Problem dims (fixed): B=8, L=128, H=768, R=24
#define BD   8
#define LD   128
#define HD   768
#define RD   24
#define H2D  384
#define NF   1536   // fused N (two heads side by side)
#define WSZ  589824 // 768*768

typedef __attribute__((ext_vector_type(8))) short bf16x8;
typedef __attribute__((ext_vector_type(4))) float f32x4;

__device__ __forceinline__ short f2bf(float f) {
    __hip_bfloat16 h = __float2bfloat16(f);
    return *reinterpret_cast<short*>(&h);
}

// ---------------------------------------------------------------------------
// Launch 1: prep. 864 blocks x 256 threads, flat blockIdx.x:
//   [0,96):    pool       (b = q/12, c = q%12; 4-way split over L)
//   [96,192):  biasrel    = re@Wtop + bias (2-way split-K); q==96 inits subj/obj
//   [192,288): embed fp32 -> bf16 (row-major, no transpose)
//   [288,864): W 64x64 tile transpose+convert: WT[n][k] = bf16(W[k][n])
//              w = (q-288)/144 in {Wcorr1, Wcorr2, Wsh_bot, Woh_bot}
__global__ __launch_bounds__(256) void prep_kernel(
        const float* __restrict__ embed, const float* __restrict__ mask,
        const float* __restrict__ rel_emb, const int* __restrict__ trel,
        const float* __restrict__ W_corr,
        const float* __restrict__ W_sh, const float* __restrict__ b_sh,
        const float* __restrict__ W_oh, const float* __restrict__ b_oh,
        const float* __restrict__ b_st, const float* __restrict__ b_ot,
        float* __restrict__ pool, float* __restrict__ biasrel,
        unsigned short* __restrict__ embedB, unsigned short* __restrict__ WT,
        float* __restrict__ out_subj, float* __restrict__ out_obj) {
    const int q = blockIdx.x, tid = threadIdx.x;

    if (q < 96) {
        // ---- pool
        const int b = q / 12, c = q % 12;
        __shared__ float mrow[LD];
        __shared__ float msum;
        __shared__ float part[4][64];
        if (tid < LD) mrow[tid] = mask[b * LD + tid];
        __syncthreads();
        if (tid == 0) {
            float s = 0.f;
            for (int l = 0; l < LD; ++l) s += mrow[l];
            msum = s;
        }
        __syncthreads();
        const int lc = tid >> 6, hh = tid & 63;
        const int h = c * 64 + hh;
        float acc = 0.f;
        const float* base = embed + ((size_t)b * LD + lc * 32) * HD + h;
#pragma unroll 8
        for (int i = 0; i < 32; ++i) acc += base[(size_t)i * HD] * mrow[lc * 32 + i];
        part[lc][hh] = acc;
        __syncthreads();
        if (lc == 0)
            pool[b * HD + h] = (part[0][hh] + part[1][hh] + part[2][hh] + part[3][hh]) / msum;
    } else if (q < 192) {
        // ---- biasrel
        const int qq = q - 96;
        const int b = qq / 12, cc = qq % 12;
        __shared__ float re[HD];
        __shared__ float part2[2][128];
        const int rel = trel[b];
        for (int k = tid; k < HD; k += 256) re[k] = rel_emb[(size_t)rel * HD + k];
        if (qq == 0 && tid < 3 * LD) {
            const int l = tid / 3, t = tid - 3 * l;
            out_subj[(l) * 3 + t] = b_st[t];   // b==0 here
            out_obj [(l) * 3 + t] = b_ot[t];
        }
        if (cc == 0 && b > 0 && tid < 3 * LD) {
            const int l = tid / 3, t = tid - 3 * l;
            out_subj[(b * LD + l) * 3 + t] = b_st[t];
            out_obj [(b * LD + l) * 3 + t] = b_ot[t];
        }
        __syncthreads();
        const int kc = tid >> 7, nn = tid & 127;
        const int n = cc * 128 + nn;
        const float* Wp; float bb; int col;
        if (n < HD) { Wp = W_sh; bb = b_sh[n];      col = n; }
        else        { Wp = W_oh; bb = b_oh[n - HD]; col = n - HD; }
        float acc = 0.f;
#pragma unroll 8
        for (int i = 0; i < 384; ++i) {
            const int k = kc * 384 + i;
            acc += re[k] * Wp[(size_t)k * HD + col];
        }
        part2[kc][nn] = acc;
        __syncthreads();
        if (kc == 0) biasrel[b * NF + n] = part2[0][nn] + part2[1][nn] + bb;
    } else if (q < 288) {
        // ---- embed convert (row-major): 8192 elems per block
        const int base = (q - 192) * 8192;
#pragma unroll
        for (int it = 0; it < 4; ++it) {
            const int off = base + it * 2048 + tid * 8;
            float4 v0 = *(const float4*)&embed[off];
            float4 v1 = *(const float4*)&embed[off + 4];
            bf16x8 p;
            p[0] = f2bf(v0.x); p[1] = f2bf(v0.y); p[2] = f2bf(v0.z); p[3] = f2bf(v0.w);
            p[4] = f2bf(v1.x); p[5] = f2bf(v1.y); p[6] = f2bf(v1.z); p[7] = f2bf(v1.w);
            *(bf16x8*)&embedB[off] = p;
        }
    } else {
        // ---- W transpose+convert, one 64x64 tile per block
        const int qq = q - 288;
        const int w = qq / 144, t = qq % 144;
        const int kt = t / 12, nt = t % 12;
        const float* src = (w == 0) ? W_corr
                         : (w == 1) ? W_corr + WSZ
                         : (w == 2) ? W_sh + WSZ
                                    : W_oh + WSZ;
        unsigned short* dst = WT + (size_t)w * WSZ;
        __shared__ float tile[64 * 65];
        const int r = tid >> 2, c4 = (tid & 3) * 16;
#pragma unroll
        for (int i = 0; i < 4; ++i) {
            float4 v = *(const float4*)&src[(size_t)(kt * 64 + r) * HD + nt * 64 + c4 + i * 4];
            tile[r * 65 + c4 + i * 4 + 0] = v.x;
            tile[r * 65 + c4 + i * 4 + 1] = v.y;
            tile[r * 65 + c4 + i * 4 + 2] = v.z;
            tile[r * 65 + c4 + i * 4 + 3] = v.w;
        }
        __syncthreads();
        bf16x8 p0, p1;
#pragma unroll
        for (int j = 0; j < 8; ++j) {
            p0[j] = f2bf(tile[(c4 + j) * 65 + r]);
            p1[j] = f2bf(tile[(c4 + 8 + j) * 65 + r]);
        }
        unsigned short* o = dst + (size_t)(nt * 64 + r) * HD + kt * 64 + c4;
        *(bf16x8*)(o)     = p0;
        *(bf16x8*)(o + 8) = p1;
    }
}

// ---------------------------------------------------------------------------
// Launch 2: biggemm. grid (27, 16), 256 threads.
//  x < 24: dual MFMA GEMM (pre-converted bf16 inputs, shared embed A-tile):
//    GEMM0: AC = embed @ [Wcorr1 | Wcorr2]
//    GEMM1: relu(embed @ [Wsh_bot | Woh_bot] + biasrel) row-dot W_st/W_ot
//           -> atomicAdd into subj/obj
//  x >= 24: relh blocks (48): rh[b,n] = relu(pool@W_hr + b_hr)
__global__ __launch_bounds__(256) void biggemm(
        const unsigned short* __restrict__ embedB,
        const unsigned short* __restrict__ WT,
        const float* __restrict__ biasrel,
        const float* __restrict__ W_st, const float* __restrict__ W_ot,
        const float* __restrict__ pool,
        const float* __restrict__ W_hr, const float* __restrict__ b_hr,
        float* __restrict__ AC, float* __restrict__ out_subj,
        float* __restrict__ out_obj, float* __restrict__ rh) {
    const int tid = threadIdx.x;

    if (blockIdx.x >= 24) {
        const int b = blockIdx.y >> 1;
        const int c = (blockIdx.x - 24) * 2 + (blockIdx.y & 1);
        __shared__ float prow[HD];
        __shared__ float rpart[4][64];
        for (int k = tid; k < HD; k += 256) prow[k] = pool[b * HD + k];
        __syncthreads();
        const int kc = tid >> 6, nn = tid & 63;
        const int n = c * 64 + nn;
        float acc = 0.f;
#pragma unroll 8
        for (int i = 0; i < 192; ++i) {
            const int k = kc * 192 + i;
            acc += prow[k] * W_hr[(size_t)k * H2D + n];
        }
        rpart[kc][nn] = acc;
        __syncthreads();
        if (kc == 0)
            rh[b * H2D + n] = fmaxf(rpart[0][nn] + rpart[1][nn] + rpart[2][nn] + rpart[3][nn] + b_hr[n], 0.f);
        return;
    }

    __shared__ __align__(16) short As [64][40];
    __shared__ __align__(16) short Bs0[64][40];
    __shared__ __align__(16) short Bs1[64][40];
    __shared__ float partial[64][3];

    const int bn0 = blockIdx.x * 64;
    const int bm0 = blockIdx.y * 64;

    const unsigned short* W0 = (bn0 < HD) ? WT : WT + WSZ;                   // corr
    const unsigned short* W1 = (bn0 < HD) ? WT + 2 * (size_t)WSZ : WT + 3 * (size_t)WSZ; // heads
    const int col0 = (bn0 < HD) ? bn0 : bn0 - HD;

    if (tid < 192) partial[tid / 3][tid % 3] = 0.f;

    // staging: row = tid>>2 (0..63), kc8 = (tid&3)*8
    const int row = tid >> 2;
    const int kc8 = (tid & 3) * 8;

    // compute indices
    const int lane = tid & 63;
    const int wv = tid >> 6;
    const int wm = (wv >> 1) * 32;
    const int wn = (wv & 1) * 32;
    const int fr = lane & 15;
    const int kq = (lane >> 4) * 8;
    const int mq = (lane >> 4) * 4;

    f32x4 c00 = {0.f,0.f,0.f,0.f}, c01 = c00, c10 = c00, c11 = c00;
    f32x4 h00 = c00, h01 = c00, h10 = c00, h11 = c00;

    for (int kt = 0; kt < 24; ++kt) {
        const int k0 = kt << 5;
        bf16x8 av = *(const bf16x8*)&embedB[(size_t)(bm0 + row) * HD + k0 + kc8];
        bf16x8 b0v = *(const bf16x8*)&W0[(size_t)(col0 + row) * HD + k0 + kc8];
        bf16x8 b1v = *(const bf16x8*)&W1[(size_t)(col0 + row) * HD + k0 + kc8];

        __syncthreads();
        *(bf16x8*)&As [row][kc8] = av;
        *(bf16x8*)&Bs0[row][kc8] = b0v;
        *(bf16x8*)&Bs1[row][kc8] = b1v;
        __syncthreads();

        bf16x8 a0 = *(bf16x8*)&As[wm + fr][kq];
        bf16x8 a1 = *(bf16x8*)&As[wm + 16 + fr][kq];
        bf16x8 b0 = *(bf16x8*)&Bs0[wn + fr][kq];
        bf16x8 b1 = *(bf16x8*)&Bs0[wn + 16 + fr][kq];
        bf16x8 d0 = *(bf16x8*)&Bs1[wn + fr][kq];
        bf16x8 d1 = *(bf16x8*)&Bs1[wn + 16 + fr][kq];
        c00 = __builtin_amdgcn_mfma_f32_16x16x32_bf16(a0, b0, c00, 0, 0, 0);
        c01 = __builtin_amdgcn_mfma_f32_16x16x32_bf16(a0, b1, c01, 0, 0, 0);
        c10 = __builtin_amdgcn_mfma_f32_16x16x32_bf16(a1, b0, c10, 0, 0, 0);
        c11 = __builtin_amdgcn_mfma_f32_16x16x32_bf16(a1, b1, c11, 0, 0, 0);
        h00 = __builtin_amdgcn_mfma_f32_16x16x32_bf16(a0, d0, h00, 0, 0, 0);
        h01 = __builtin_amdgcn_mfma_f32_16x16x32_bf16(a0, d1, h01, 0, 0, 0);
        h10 = __builtin_amdgcn_mfma_f32_16x16x32_bf16(a1, d0, h10, 0, 0, 0);
        h11 = __builtin_amdgcn_mfma_f32_16x16x32_bf16(a1, d1, h11, 0, 0, 0);
    }

    // ---- GEMM0 epilogue: store AC tile. C/D layout col=lane&15, row=quad*4+reg.
#pragma unroll
    for (int i = 0; i < 2; ++i) {
#pragma unroll
        for (int j = 0; j < 2; ++j) {
            f32x4 a = (i == 0) ? (j == 0 ? c00 : c01) : (j == 0 ? c10 : c11);
            const int ncol = bn0 + wn + j * 16 + fr;
#pragma unroll
            for (int r = 0; r < 4; ++r) {
                const int mrow = bm0 + wm + i * 16 + mq + r;
                AC[(size_t)mrow * NF + ncol] = a[r];
            }
        }
    }

    // ---- GEMM1 epilogue
    {
        const float* brl = biasrel + (size_t)(bm0 / LD) * NF;
        const float* Wt = (bn0 < HD) ? W_st : W_ot;
        float* op = (bn0 < HD) ? out_subj : out_obj;
        float pt[8][3] = {};
#pragma unroll
        for (int j = 0; j < 2; ++j) {
            const int ncol = bn0 + wn + j * 16 + fr;
            const int ncl = (bn0 < HD) ? ncol : ncol - HD;
            const float wt0 = Wt[ncl * 3 + 0];
            const float wt1 = Wt[ncl * 3 + 1];
            const float wt2 = Wt[ncl * 3 + 2];
            const float bias = brl[ncol];
#pragma unroll
            for (int i = 0; i < 2; ++i) {
                f32x4 a = (i == 0) ? (j == 0 ? h00 : h01) : (j == 0 ? h10 : h11);
#pragma unroll
                for (int r = 0; r < 4; ++r) {
                    const float v = fmaxf(a[r] + bias, 0.f);
                    pt[i * 4 + r][0] += v * wt0;
                    pt[i * 4 + r][1] += v * wt1;
                    pt[i * 4 + r][2] += v * wt2;
                }
            }
        }
#pragma unroll
        for (int mask = 1; mask < 16; mask <<= 1) {
#pragma unroll
            for (int x = 0; x < 8; ++x)
#pragma unroll
                for (int t = 0; t < 3; ++t)
                    pt[x][t] += __shfl_xor(pt[x][t], mask, 64);
        }
        if (fr == 0) {
#pragma unroll
            for (int i = 0; i < 2; ++i)
#pragma unroll
                for (int r = 0; r < 4; ++r)
#pragma unroll
                    for (int t = 0; t < 3; ++t)
                        atomicAdd(&partial[wm + i * 16 + mq + r][t], pt[i * 4 + r][t]);
        }
        __syncthreads();
        if (tid < 192) {
            const int m = tid / 3, t = tid % 3;
            atomicAdd(&op[(size_t)(bm0 + m) * 3 + t], partial[m][t]);
        }
    }
}

// ---------------------------------------------------------------------------
// Launch 3: corres + stage1. grid (33, 8), 512 threads (8 waves).
//  x < 32: pred_corres[b, i0..i0+4, :] ; x == 32: stage1 for batch y
__global__ __launch_bounds__(512) void corres_kernel(
        const float* __restrict__ AC,
        const float* __restrict__ b_corr, const float* __restrict__ W_gc,
        const float* __restrict__ b_gc,
        const float* __restrict__ rh,
        const float* __restrict__ W_rj, const float* __restrict__ b_rj,
        float* __restrict__ out, float* __restrict__ out_stage1) {
    const int b = blockIdx.y;
    const int tid = threadIdx.x;

    if (blockIdx.x == 32) {
        __shared__ float rl[H2D];
        __shared__ float spart[8][RD];
        if (tid < H2D) rl[tid] = rh[b * H2D + tid];
        __syncthreads();
        if (tid < 8 * RD) {
            const int n = tid % RD, kc = tid / RD;
            float acc = 0.f;
#pragma unroll 8
            for (int i = 0; i < 48; ++i) {
                const int k = kc * 48 + i;
                acc += rl[k] * W_rj[k * RD + n];
            }
            spart[kc][n] = acc;
        }
        __syncthreads();
        if (tid < RD) {
            float s = b_rj[tid];
#pragma unroll
            for (int q = 0; q < 8; ++q) s += spart[q][tid];
            out_stage1[b * RD + tid] = s;
        }
        return;
    }

    const int i0 = blockIdx.x * 4;
    const int lane = tid & 63;
    const int wave = tid >> 6;  // 0..7

    f32x4 wg[3], cb[4][3];
#pragma unroll
    for (int s = 0; s < 3; ++s) {
        const int h = s * 256 + lane * 4;
        f32x4 w = *(const f32x4*)&W_gc[h];
        f32x4 bc = *(const f32x4*)&b_corr[h];
        wg[s] = w;
#pragma unroll
        for (int i = 0; i < 4; ++i) {
            f32x4 cv = *(const f32x4*)&AC[((size_t)(b * LD + i0 + i)) * NF + HD + h];
            cb[i][s] = cv + bc;
        }
    }
    const float bg = b_gc[0];

    for (int j = wave; j < LD; j += 8) {
        const float* arow = AC + ((size_t)(b * LD + j)) * NF;
        f32x4 a[3];
#pragma unroll
        for (int s = 0; s < 3; ++s) a[s] = *(const f32x4*)&arow[s * 256 + lane * 4];
        float sum[4] = {0.f, 0.f, 0.f, 0.f};
#pragma unroll
        for (int s = 0; s < 3; ++s) {
#pragma unroll
            for (int i = 0; i < 4; ++i) {
                f32x4 v = a[s] + cb[i][s];
#pragma unroll
                for (int t = 0; t < 4; ++t)
                    sum[i] += fmaxf(v[t], 0.f) * wg[s][t];
            }
        }
#pragma unroll
        for (int off = 32; off > 0; off >>= 1) {
#pragma unroll
            for (int i = 0; i < 4; ++i) sum[i] += __shfl_down(sum[i], off, 64);
        }
        if (lane == 0) {
#pragma unroll
            for (int i = 0; i < 4; ++i)
                out[((size_t)(b * LD + i0 + i)) * LD + j] = sum[i] + bg;
        }
    }
}

// ---------------------------------------------------------------------------
extern "C" void kernel_launch(void* const* d_in, const int* in_sizes, int n_in,
                              void* d_out, int out_size, void* d_ws, size_t ws_size,
                              hipStream_t stream) {
    const float* embed   = (const float*)d_in[0];
    const float* mask    = (const float*)d_in[1];
    const int*   trel    = (const int*)d_in[2];
    const float* W_hr    = (const float*)d_in[3];
    const float* b_hr    = (const float*)d_in[4];
    const float* W_rj    = (const float*)d_in[5];
    const float* b_rj    = (const float*)d_in[6];
    const float* rel_emb = (const float*)d_in[7];
    const float* W_corr  = (const float*)d_in[8];
    const float* b_corr  = (const float*)d_in[9];
    const float* W_gc    = (const float*)d_in[10];
    const float* b_gc    = (const float*)d_in[11];
    const float* W_sh    = (const float*)d_in[12];
    const float* b_sh    = (const float*)d_in[13];
    const float* W_st    = (const float*)d_in[14];
    const float* b_st    = (const float*)d_in[15];
    const float* W_oh    = (const float*)d_in[16];
    const float* b_oh    = (const float*)d_in[17];
    const float* W_ot    = (const float*)d_in[18];
    const float* b_ot    = (const float*)d_in[19];
    float* out = (float*)d_out;

    float* ws      = (float*)d_ws;
    float* AC      = ws;                             // 1,572,864 floats
    float* biasrel = ws + 1572864;                   // 12,288
    float* rh      = ws + 1572864 + 12288;           // 3,072
    float* pool    = ws + 1572864 + 12288 + 3072;    // 6,144
    unsigned short* embedB = (unsigned short*)(ws + 1594368);          // 786,432 shorts
    unsigned short* WT     = (unsigned short*)(ws + 1594368 + 393216); // 4*589,824 shorts

    // Output layout: stage1[192] | subj[3072] | obj[3072] | pred_corres[131072]
    float* out_stage1 = out;
    float* out_subj   = out + 192;
    float* out_obj    = out + 3264;
    float* out_corr   = out + 6336;

    prep_kernel<<<864, 256, 0, stream>>>(embed, mask, rel_emb, trel, W_corr,
                                         W_sh, b_sh, W_oh, b_oh, b_st, b_ot,
                                         pool, biasrel, embedB, WT,
                                         out_subj, out_obj);

    biggemm<<<dim3(27, 16), 256, 0, stream>>>(embedB, WT, biasrel, W_st, W_ot,
                                              pool, W_hr, b_hr,
                                              AC, out_subj, out_obj, rh);

    corres_kernel<<<dim3(33, BD), 512, 0, stream>>>(AC, b_corr, W_gc, b_gc,
                                                    rh, W_rj, b_rj, out_corr, out_stage1);
}